// Round 8
// baseline (114.959 us; speedup 1.0000x reference)
//
#include <hip/hip_runtime.h>

#define M_TOT 4096
#define B_TOT 8
#define N_TOT 512
#define FD    128
#define BD    128
#define BVD   6
#define H     64
#define MAX_TILES 264   // 4096/16 + 8 ragged tails

typedef short short8 __attribute__((ext_vector_type(8)));   // 8 bf16 = 4 VGPRs (MFMA A/B frag)
typedef float floatx4 __attribute__((ext_vector_type(4)));  // MFMA C/D frag

__device__ __forceinline__ unsigned short f2bf(float x) {   // RNE float->bf16
    union { float f; unsigned int u; } v; v.f = x;
    return (unsigned short)((v.u + 0x7fffu + ((v.u >> 16) & 1u)) >> 16);
}
__device__ __forceinline__ float bf2f(unsigned short u) {
    union { unsigned int u32; float f; } v; v.u32 = ((unsigned int)u) << 16;
    return v.f;
}

__device__ __forceinline__ int lb_dev(const int* __restrict__ arr, int n, int v) {
    int lo = 0, hi = n;
    while (lo < hi) { int mid = (lo + hi) >> 1; if (arr[mid] < v) lo = mid + 1; else hi = mid; }
    return lo;
}

// ---------------------------------------------------------------------------
// K_pre: roles by blockIdx (unchanged — measured cheap):
//   [0,256)    f_bf[m][h]      (bf16)
//   [256,512)  bFT_bf[b][n][h] (bf16, transposed)
//   [512,768)  bv_bf[b][h][n]  (bf16)
//   768        tile table + Wo_bf
// ---------------------------------------------------------------------------
__global__ __launch_bounds__(256) void k_pre(const float* __restrict__ f_pre_in,
                                             const int*   __restrict__ batch,
                                             const float* __restrict__ b_pre_in,
                                             const float* __restrict__ bv_in,
                                             const float* __restrict__ Wf,
                                             const float* __restrict__ bf,
                                             const float* __restrict__ Wb,
                                             const float* __restrict__ bb,
                                             const float* __restrict__ Wbv,
                                             const float* __restrict__ bbv,
                                             const float* __restrict__ Wo,
                                             unsigned short* __restrict__ f_bf,
                                             unsigned short* __restrict__ bFT_bf,
                                             unsigned short* __restrict__ bv_bf,
                                             unsigned short* __restrict__ Wo_bf,
                                             int4*  __restrict__ table) {
    __shared__ __align__(16) char sm[43264];
    const int t = threadIdx.x;
    const int blk = blockIdx.x;

    if (blk < 256) {
        // ---- f role: 16 m x 64 h per block ----
        float* fpre = (float*)sm;           // [16][132]
        float* WfT  = (float*)(sm + 8448);  // [128][68]
        const int m0 = blk * 16;
        for (int i = t; i < 16 * FD; i += 256)
            fpre[(i >> 7) * 132 + (i & 127)] = f_pre_in[(size_t)m0 * FD + i];
        for (int i = t; i < H * FD; i += 256)
            WfT[(i & 127) * 68 + (i >> 7)] = Wf[i];
        __syncthreads();
        const int mi = t >> 4;
        const int h4 = (t & 15) * 4;
        float a0 = bf[h4], a1 = bf[h4 + 1], a2 = bf[h4 + 2], a3 = bf[h4 + 3];
#pragma unroll 4
        for (int d4 = 0; d4 < 32; ++d4) {
            const float4 fp = *(const float4*)&fpre[mi * 132 + d4 * 4];
            const float* fpp = &fp.x;
#pragma unroll
            for (int i = 0; i < 4; ++i) {
                const float4 wv = *(const float4*)&WfT[(d4 * 4 + i) * 68 + h4];
                const float f = fpp[i];
                a0 += f * wv.x; a1 += f * wv.y; a2 += f * wv.z; a3 += f * wv.w;
            }
        }
        ushort4 o; o.x = f2bf(a0); o.y = f2bf(a1); o.z = f2bf(a2); o.w = f2bf(a3);
        *(ushort4*)&f_bf[(size_t)(m0 + mi) * H + h4] = o;
    } else if (blk < 512) {
        // ---- bFT role: block = (b, 16-n chunk); thread = (h, 4 n) ----
        float* Wb_l = (float*)sm;            // [64][129]
        float* bp   = (float*)(sm + 33024);  // [128][17]
        const int idx = blk - 256;
        const int b  = idx >> 5;
        const int n0 = (idx & 31) * 16;
        for (int i = t; i < H * BD; i += 256)
            Wb_l[(i >> 7) * 129 + (i & 127)] = Wb[i];
        for (int i = t; i < BD * 16; i += 256)
            bp[(i >> 4) * 17 + (i & 15)] =
                b_pre_in[(size_t)b * BD * N_TOT + (size_t)(i >> 4) * N_TOT + n0 + (i & 15)];
        __syncthreads();
        const int h  = t & 63;
        const int nl = t >> 6;
        const float bias = bb[h];
        float acc[4] = {bias, bias, bias, bias};
        const float* wr = &Wb_l[h * 129];
#pragma unroll 8
        for (int d = 0; d < BD; ++d) {
            const float w = wr[d];
            acc[0] += w * bp[d * 17 + nl];
            acc[1] += w * bp[d * 17 + nl + 4];
            acc[2] += w * bp[d * 17 + nl + 8];
            acc[3] += w * bp[d * 17 + nl + 12];
        }
#pragma unroll
        for (int j = 0; j < 4; ++j)
            bFT_bf[((size_t)b * N_TOT + n0 + nl + 4 * j) * H + h] = f2bf(acc[j]);
    } else if (blk < 768) {
        // ---- bv role: block = (b, 2 h); thread = 4 n ----
        const int idx = blk - 512;
        const int b  = idx >> 5;
        const int h  = (idx & 31) * 2 + (t >> 7);
        const int n4 = (t & 127) * 4;
        float w[BVD];
#pragma unroll
        for (int c = 0; c < BVD; ++c) w[c] = Wbv[h * BVD + c];
        const float bias = bbv[h];
        float a0 = bias, a1 = bias, a2 = bias, a3 = bias;
        const float* src = bv_in + (size_t)b * BVD * N_TOT + n4;
#pragma unroll
        for (int c = 0; c < BVD; ++c) {
            const float4 v = *(const float4*)(src + c * N_TOT);
            a0 += w[c] * v.x; a1 += w[c] * v.y; a2 += w[c] * v.z; a3 += w[c] * v.w;
        }
        ushort4 o; o.x = f2bf(a0); o.y = f2bf(a1); o.z = f2bf(a2); o.w = f2bf(a3);
        *(ushort4*)&bv_bf[((size_t)b * H + h) * N_TOT + n4] = o;
    } else {
        // ---- misc role: tile table + Wo bf16 ----
        int starts[9];
#pragma unroll
        for (int b = 0; b <= 8; ++b) starts[b] = lb_dev(batch, M_TOT, b);
        int pre[9]; pre[0] = 0;
#pragma unroll
        for (int b = 0; b < 8; ++b) pre[b + 1] = pre[b] + (starts[b + 1] - starts[b] + 15) / 16;
        const int total = pre[8];
        for (int idx = t; idx < MAX_TILES; idx += 256) {
            int4 e = make_int4(0, 0, 0, 0);
            if (idx < total) {
                int b = 0;
                while (pre[b + 1] <= idx) ++b;
                const int r0 = starts[b] + (idx - pre[b]) * 16;
                e.x = b; e.y = r0; e.z = min(16, starts[b + 1] - r0);
            }
            table[idx] = e;
        }
        for (int i = t; i < H * 2 * H; i += 256) Wo_bf[i] = f2bf(Wo[i]);
    }
}

// ---------------------------------------------------------------------------
// K_main v8: 512 thr / 8 waves, wave = (eg = wave>>2, n-quarter = wave&3).
// Each wave does HALF of R7's work (one of euc/geo), fully wave-private until
// the same two barriers -> 2 independent waves/SIMD for latency co-scheduling,
// with none of R6's cross-wave k-loop coupling.
// ---------------------------------------------------------------------------
__global__ __launch_bounds__(512) void k_main(const unsigned short* __restrict__ f_bf,
                                              const unsigned short* __restrict__ bFT_bf,
                                              const unsigned short* __restrict__ bv_bf,
                                              const unsigned short* __restrict__ Wo_bf,
                                              const float* __restrict__ bo,
                                              const int4*  __restrict__ table,
                                              float* __restrict__ out) {
    // per-wave region: W bf16 [16 r][136 n-local] = 4352 B; later aliased as
    // O-partials f32 [64 h][16 r] = 4096 B (wave-local, program order).
    __shared__ __align__(16) char wreg[8][4352];
    __shared__ __align__(16) float rowsumP[8][16];
    __shared__ __align__(16) unsigned short cat_l[16 * 136];

    const int t = threadIdx.x;
    const int wave = t >> 6, l = t & 63, quad = l >> 4, s = l & 15;
    const int eg = wave >> 2;        // 0 = euc, 1 = geo
    const int nq = wave & 3;         // n-quarter
    const int4 te = table[blockIdx.x];
    const int b = te.x, m0 = te.y, nr = te.z;
    if (nr == 0) return;

    unsigned short* Wl = (unsigned short*)&wreg[wave][0];
    const floatx4 zero = {0.f, 0.f, 0.f, 0.f};

    // ================= register prefetch (independent of LDS) ===============
    // f B-frag for this eg (rows clamped for ragged tiles)
    const int rclamp = (s < nr) ? s : (nr - 1);
    const short8 fX = *(const short8*)(f_bf + (size_t)(m0 + rclamp) * H + eg * 32 + quad * 8);
    // bv B-frags for phase 3: [kc][hc] over this wave's n-quarter
    short8 bvF[4][4];
#pragma unroll
    for (int kc = 0; kc < 4; ++kc)
#pragma unroll
        for (int hc = 0; hc < 4; ++hc)
            bvF[kc][hc] = *(const short8*)(bv_bf +
                ((size_t)b * H + hc * 16 + s) * N_TOT + nq * 128 + kc * 32 + quad * 8);
    // Wo B-frags + bias for phase 5 (waves 0-3 use them)
    short8 woF[4];
#pragma unroll
    for (int kc = 0; kc < 4; ++kc)
        woF[kc] = *(const short8*)(Wo_bf + (size_t)((wave & 3) * 16 + s) * 128 + kc * 32 + quad * 8);
    const float bj = bo[(wave & 3) * 16 + s];
    // ========================================================================

    // ---- phase 1: scores S^T for this (eg, n-quarter): 8 MFMA ----
    const unsigned short* bA = bFT_bf + ((size_t)b * N_TOT + nq * 128 + s) * H + eg * 32 + quad * 8;
    floatx4 d[8];
#pragma unroll
    for (int c = 0; c < 8; ++c) {
        const short8 aX = *(const short8*)(bA + (size_t)c * 16 * H);
        d[c] = __builtin_amdgcn_mfma_f32_16x16x32_bf16(aX, fX, zero, 0, 0, 0);
    }

    // ---- phase 2: exp, bf16 round, pack -> W_lds; rowsums ----
    float rs = 0.f;
#pragma unroll
    for (int c = 0; c < 8; ++c) {
        ushort4 p;
        unsigned short u;
        u = f2bf(__expf(d[c][0] * 0.125f)); rs += bf2f(u); p.x = u;
        u = f2bf(__expf(d[c][1] * 0.125f)); rs += bf2f(u); p.y = u;
        u = f2bf(__expf(d[c][2] * 0.125f)); rs += bf2f(u); p.z = u;
        u = f2bf(__expf(d[c][3] * 0.125f)); rs += bf2f(u); p.w = u;
        // lane holds rows n-local = c*16 + quad*4 + reg, col r = s
        *(ushort4*)&Wl[s * 136 + c * 16 + quad * 4] = p;
    }
    rs += __shfl_xor(rs, 16); rs += __shfl_xor(rs, 32);
    if (l < 16) rowsumP[wave][s] = rs;

    // ---- phase 3: PV for this eg over the wave's 128 n: 16 MFMA ----
    floatx4 o[4] = {zero, zero, zero, zero};
#pragma unroll
    for (int kc = 0; kc < 4; ++kc) {
        const short8 aW = *(const short8*)&Wl[s * 136 + kc * 32 + quad * 8];
#pragma unroll
        for (int hc = 0; hc < 4; ++hc)
            o[hc] = __builtin_amdgcn_mfma_f32_16x16x32_bf16(aW, bvF[kc][hc], o[hc], 0, 0, 0);
    }
    // write O partials into the (now consumed) W region: [h][16 r] f32
    {
        float* Op = (float*)&wreg[wave][0];
#pragma unroll
        for (int hc = 0; hc < 4; ++hc)
            *(floatx4*)&Op[(hc * 16 + s) * 16 + quad * 4] = o[hc];
    }
    __syncthreads();

    // ---- phase 4: reduce 4 n-quarters per eg + normalize -> cat bf16 ----
    {
        const int h  = t >> 3;           // 64
        const int ge = (t >> 2) & 1;     // eg
        const int r4 = (t & 3) * 4;
        floatx4 sm_ = zero, rsum = zero;
#pragma unroll
        for (int w = 0; w < 4; ++w) {
            const float* opw = (const float*)&wreg[ge * 4 + w][0];
            sm_  += *(const floatx4*)&opw[h * 16 + r4];
            rsum += *(const floatx4*)&rowsumP[ge * 4 + w][r4];
        }
#pragma unroll
        for (int i = 0; i < 4; ++i)
            cat_l[(r4 + i) * 136 + ge * 64 + h] = f2bf(sm_[i] / rsum[i]);
    }
    __syncthreads();

    // ---- phase 5: out = cat @ Wo^T + bo (waves 0-3, j-tile = wave) ----
    if (wave < 4) {
        floatx4 acc = zero;
#pragma unroll
        for (int kc = 0; kc < 4; ++kc) {
            const short8 aC = *(const short8*)&cat_l[s * 136 + kc * 32 + quad * 8];
            acc = __builtin_amdgcn_mfma_f32_16x16x32_bf16(aC, woF[kc], acc, 0, 0, 0);
        }
        const int j = wave * 16 + s;
#pragma unroll
        for (int reg = 0; reg < 4; ++reg) {
            const int r = quad * 4 + reg;
            if (r < nr) out[(size_t)(m0 + r) * H + j] = acc[reg] + bj;
        }
    }
}

extern "C" void kernel_launch(void* const* d_in, const int* in_sizes, int n_in,
                              void* d_out, int out_size, void* d_ws, size_t ws_size,
                              hipStream_t stream) {
    const float* f_pre_in = (const float*)d_in[0];
    const int*   f_batch  = (const int*)  d_in[1];
    const float* b_pre_in = (const float*)d_in[2];
    const float* bv_in    = (const float*)d_in[3];
    const float* Wf       = (const float*)d_in[4];
    const float* bf       = (const float*)d_in[5];
    const float* Wb       = (const float*)d_in[6];
    const float* bb       = (const float*)d_in[7];
    const float* Wbv      = (const float*)d_in[8];
    const float* bbv      = (const float*)d_in[9];
    const float* Wo       = (const float*)d_in[10];
    const float* bo       = (const float*)d_in[11];
    float* out = (float*)d_out;

    // ws layout (ushort elements, then table)
    unsigned short* f_bf   = (unsigned short*)d_ws;            // 4096*64
    unsigned short* bFT_bf = f_bf + (size_t)M_TOT * H;         // 8*512*64
    unsigned short* bv_bf  = bFT_bf + (size_t)B_TOT * N_TOT * H;
    unsigned short* Wo_bf  = bv_bf + (size_t)B_TOT * H * N_TOT;
    int4* table = (int4*)(Wo_bf + (size_t)H * 2 * H);          // 16B-aligned

    k_pre <<<769, 256, 0, stream>>>(f_pre_in, f_batch, b_pre_in, bv_in,
                                    Wf, bf, Wb, bb, Wbv, bbv, Wo,
                                    f_bf, bFT_bf, bv_bf, Wo_bf, table);
    k_main<<<MAX_TILES, 512, 0, stream>>>(f_bf, bFT_bf, bv_bf, Wo_bf, bo, table, out);
}

// Round 9
// 108.683 us; speedup vs baseline: 1.0577x; 1.0577x over previous
//
#include <hip/hip_runtime.h>

#define M_TOT 4096
#define B_TOT 8
#define N_TOT 512
#define FD    128
#define BD    128
#define BVD   6
#define H     64
#define MAX_TILES 264   // 4096/16 + 8 ragged tails

typedef short short8 __attribute__((ext_vector_type(8)));   // 8 bf16 = 4 VGPRs (MFMA A/B frag)
typedef float floatx4 __attribute__((ext_vector_type(4)));  // MFMA C/D frag

__device__ __forceinline__ unsigned short f2bf(float x) {   // RNE float->bf16
    union { float f; unsigned int u; } v; v.f = x;
    return (unsigned short)((v.u + 0x7fffu + ((v.u >> 16) & 1u)) >> 16);
}
__device__ __forceinline__ float bf2f(unsigned short u) {
    union { unsigned int u32; float f; } v; v.u32 = ((unsigned int)u) << 16;
    return v.f;
}

__device__ __forceinline__ int lb_dev(const int* __restrict__ arr, int n, int v) {
    int lo = 0, hi = n;
    while (lo < hi) { int mid = (lo + hi) >> 1; if (arr[mid] < v) lo = mid + 1; else hi = mid; }
    return lo;
}

// ---------------------------------------------------------------------------
// K_pre: roles by blockIdx:
//   [0,256)    f_bf[m][h]      (bf16)
//   [256,512)  bFT_bf[b][n][h] (bf16, transposed)
//   [512,768)  bv_bf[b][h][n]  (bf16)
//   768        tile table + Wo_bf
// ---------------------------------------------------------------------------
__global__ __launch_bounds__(256) void k_pre(const float* __restrict__ f_pre_in,
                                             const int*   __restrict__ batch,
                                             const float* __restrict__ b_pre_in,
                                             const float* __restrict__ bv_in,
                                             const float* __restrict__ Wf,
                                             const float* __restrict__ bf,
                                             const float* __restrict__ Wb,
                                             const float* __restrict__ bb,
                                             const float* __restrict__ Wbv,
                                             const float* __restrict__ bbv,
                                             const float* __restrict__ Wo,
                                             unsigned short* __restrict__ f_bf,
                                             unsigned short* __restrict__ bFT_bf,
                                             unsigned short* __restrict__ bv_bf,
                                             unsigned short* __restrict__ Wo_bf,
                                             int4*  __restrict__ table) {
    __shared__ __align__(16) char sm[43264];
    const int t = threadIdx.x;
    const int blk = blockIdx.x;

    if (blk < 256) {
        // ---- f role: 16 m x 64 h per block ----
        float* fpre = (float*)sm;           // [16][132]
        float* WfT  = (float*)(sm + 8448);  // [128][68]
        const int m0 = blk * 16;
        for (int i = t; i < 16 * FD; i += 256)
            fpre[(i >> 7) * 132 + (i & 127)] = f_pre_in[(size_t)m0 * FD + i];
        for (int i = t; i < H * FD; i += 256)
            WfT[(i & 127) * 68 + (i >> 7)] = Wf[i];
        __syncthreads();
        const int mi = t >> 4;
        const int h4 = (t & 15) * 4;
        float a0 = bf[h4], a1 = bf[h4 + 1], a2 = bf[h4 + 2], a3 = bf[h4 + 3];
#pragma unroll 4
        for (int d4 = 0; d4 < 32; ++d4) {
            const float4 fp = *(const float4*)&fpre[mi * 132 + d4 * 4];
            const float* fpp = &fp.x;
#pragma unroll
            for (int i = 0; i < 4; ++i) {
                const float4 wv = *(const float4*)&WfT[(d4 * 4 + i) * 68 + h4];
                const float f = fpp[i];
                a0 += f * wv.x; a1 += f * wv.y; a2 += f * wv.z; a3 += f * wv.w;
            }
        }
        ushort4 o; o.x = f2bf(a0); o.y = f2bf(a1); o.z = f2bf(a2); o.w = f2bf(a3);
        *(ushort4*)&f_bf[(size_t)(m0 + mi) * H + h4] = o;
    } else if (blk < 512) {
        // ---- bFT role: block = (b, 16-n chunk); thread = (h, 4 n) ----
        float* Wb_l = (float*)sm;            // [64][129]
        float* bp   = (float*)(sm + 33024);  // [128][17]
        const int idx = blk - 256;
        const int b  = idx >> 5;
        const int n0 = (idx & 31) * 16;
        for (int i = t; i < H * BD; i += 256)
            Wb_l[(i >> 7) * 129 + (i & 127)] = Wb[i];
        for (int i = t; i < BD * 16; i += 256)
            bp[(i >> 4) * 17 + (i & 15)] =
                b_pre_in[(size_t)b * BD * N_TOT + (size_t)(i >> 4) * N_TOT + n0 + (i & 15)];
        __syncthreads();
        const int h  = t & 63;
        const int nl = t >> 6;
        const float bias = bb[h];
        float acc[4] = {bias, bias, bias, bias};
        const float* wr = &Wb_l[h * 129];
#pragma unroll 8
        for (int d = 0; d < BD; ++d) {
            const float w = wr[d];
            acc[0] += w * bp[d * 17 + nl];
            acc[1] += w * bp[d * 17 + nl + 4];
            acc[2] += w * bp[d * 17 + nl + 8];
            acc[3] += w * bp[d * 17 + nl + 12];
        }
#pragma unroll
        for (int j = 0; j < 4; ++j)
            bFT_bf[((size_t)b * N_TOT + n0 + nl + 4 * j) * H + h] = f2bf(acc[j]);
    } else if (blk < 768) {
        // ---- bv role: block = (b, 2 h); thread = 4 n ----
        const int idx = blk - 512;
        const int b  = idx >> 5;
        const int h  = (idx & 31) * 2 + (t >> 7);
        const int n4 = (t & 127) * 4;
        float w[BVD];
#pragma unroll
        for (int c = 0; c < BVD; ++c) w[c] = Wbv[h * BVD + c];
        const float bias = bbv[h];
        float a0 = bias, a1 = bias, a2 = bias, a3 = bias;
        const float* src = bv_in + (size_t)b * BVD * N_TOT + n4;
#pragma unroll
        for (int c = 0; c < BVD; ++c) {
            const float4 v = *(const float4*)(src + c * N_TOT);
            a0 += w[c] * v.x; a1 += w[c] * v.y; a2 += w[c] * v.z; a3 += w[c] * v.w;
        }
        ushort4 o; o.x = f2bf(a0); o.y = f2bf(a1); o.z = f2bf(a2); o.w = f2bf(a3);
        *(ushort4*)&bv_bf[((size_t)b * H + h) * N_TOT + n4] = o;
    } else {
        // ---- misc role: tile table + Wo bf16 ----
        int starts[9];
#pragma unroll
        for (int b = 0; b <= 8; ++b) starts[b] = lb_dev(batch, M_TOT, b);
        int pre[9]; pre[0] = 0;
#pragma unroll
        for (int b = 0; b < 8; ++b) pre[b + 1] = pre[b] + (starts[b + 1] - starts[b] + 15) / 16;
        const int total = pre[8];
        for (int idx = t; idx < MAX_TILES; idx += 256) {
            int4 e = make_int4(0, 0, 0, 0);
            if (idx < total) {
                int b = 0;
                while (pre[b + 1] <= idx) ++b;
                const int r0 = starts[b] + (idx - pre[b]) * 16;
                e.x = b; e.y = r0; e.z = min(16, starts[b + 1] - r0);
            }
            table[idx] = e;
        }
        for (int i = t; i < H * 2 * H; i += 256) Wo_bf[i] = f2bf(Wo[i]);
    }
}

// ---------------------------------------------------------------------------
// K_main (measured-best structure, R5/R7): 256 thr / 4 waves, wave = n-quarter;
// register prefetch of all barrier/chain-trapped global fragments at entry.
// ---------------------------------------------------------------------------
__global__ __launch_bounds__(256) void k_main(const unsigned short* __restrict__ f_bf,
                                              const unsigned short* __restrict__ bFT_bf,
                                              const unsigned short* __restrict__ bv_bf,
                                              const unsigned short* __restrict__ Wo_bf,
                                              const float* __restrict__ bo,
                                              const int4*  __restrict__ table,
                                              float* __restrict__ out) {
    // per-wave region: W bf16 [2 eg][16 r][136 n] = 8704 B; later reused as
    // O-partials f32 [2 eg][64 h][16 r] = 8192 B (wave-local alias, program order).
    __shared__ __align__(16) char wreg[4][8704];
    __shared__ __align__(16) float rowsumP[4][2][16];
    __shared__ __align__(16) unsigned short cat_l[16 * 136];

    const int t = threadIdx.x;
    const int wave = t >> 6, l = t & 63, quad = l >> 4, s = l & 15;
    const int4 te = table[blockIdx.x];
    const int b = te.x, m0 = te.y, nr = te.z;
    if (nr == 0) return;

    unsigned short* Wl = (unsigned short*)&wreg[wave][0];
    const floatx4 zero = {0.f, 0.f, 0.f, 0.f};

    // ================= register prefetch (all independent of LDS) ==========
    const int rclamp = (s < nr) ? s : (nr - 1);
    const unsigned short* fptr = f_bf + (size_t)(m0 + rclamp) * H + quad * 8;
    const short8 fE = *(const short8*)(fptr);
    const short8 fG = *(const short8*)(fptr + 32);
    short8 bvF[4][4];
#pragma unroll
    for (int kc = 0; kc < 4; ++kc)
#pragma unroll
        for (int hc = 0; hc < 4; ++hc)
            bvF[kc][hc] = *(const short8*)(bv_bf +
                ((size_t)b * H + hc * 16 + s) * N_TOT + wave * 128 + kc * 32 + quad * 8);
    short8 woF[4];
#pragma unroll
    for (int kc = 0; kc < 4; ++kc)
        woF[kc] = *(const short8*)(Wo_bf + (size_t)(wave * 16 + s) * 128 + kc * 32 + quad * 8);
    const float bj = bo[wave * 16 + s];
    // ========================================================================

    // ---- phase 1: scores S^T, 8 chunks of 16 n ----
    const unsigned short* bA = bFT_bf + ((size_t)b * N_TOT + wave * 128 + s) * H + quad * 8;
    floatx4 dE[8], dG[8];
#pragma unroll
    for (int c = 0; c < 8; ++c) {
        const short8 aE = *(const short8*)(bA + (size_t)c * 16 * H);
        const short8 aG = *(const short8*)(bA + (size_t)c * 16 * H + 32);
        dE[c] = __builtin_amdgcn_mfma_f32_16x16x32_bf16(aE, fE, zero, 0, 0, 0);
        dG[c] = __builtin_amdgcn_mfma_f32_16x16x32_bf16(aG, fG, zero, 0, 0, 0);
    }

    // ---- phase 2: exp, bf16 round, pack -> W_lds; rowsums ----
    float rsE = 0.f, rsG = 0.f;
#pragma unroll
    for (int c = 0; c < 8; ++c) {
        ushort4 pE, pG;
        unsigned short u;
        u = f2bf(__expf(dE[c][0] * 0.125f)); rsE += bf2f(u); pE.x = u;
        u = f2bf(__expf(dE[c][1] * 0.125f)); rsE += bf2f(u); pE.y = u;
        u = f2bf(__expf(dE[c][2] * 0.125f)); rsE += bf2f(u); pE.z = u;
        u = f2bf(__expf(dE[c][3] * 0.125f)); rsE += bf2f(u); pE.w = u;
        u = f2bf(__expf(dG[c][0] * 0.125f)); rsG += bf2f(u); pG.x = u;
        u = f2bf(__expf(dG[c][1] * 0.125f)); rsG += bf2f(u); pG.y = u;
        u = f2bf(__expf(dG[c][2] * 0.125f)); rsG += bf2f(u); pG.z = u;
        u = f2bf(__expf(dG[c][3] * 0.125f)); rsG += bf2f(u); pG.w = u;
        *(ushort4*)&Wl[s * 136 + c * 16 + quad * 4]        = pE;
        *(ushort4*)&Wl[2176 + s * 136 + c * 16 + quad * 4] = pG;
    }
    rsE += __shfl_xor(rsE, 16); rsE += __shfl_xor(rsE, 32);
    rsG += __shfl_xor(rsG, 16); rsG += __shfl_xor(rsG, 32);
    if (l < 16) { rowsumP[wave][0][s] = rsE; rowsumP[wave][1][s] = rsG; }

    // ---- phase 3: PV (A from own-wave W_lds; B pre-loaded in regs) ----
    floatx4 oE[4] = {zero, zero, zero, zero};
    floatx4 oG[4] = {zero, zero, zero, zero};
#pragma unroll
    for (int kc = 0; kc < 4; ++kc) {
        const short8 aE = *(const short8*)&Wl[s * 136 + kc * 32 + quad * 8];
        const short8 aG = *(const short8*)&Wl[2176 + s * 136 + kc * 32 + quad * 8];
#pragma unroll
        for (int hc = 0; hc < 4; ++hc) {
            oE[hc] = __builtin_amdgcn_mfma_f32_16x16x32_bf16(aE, bvF[kc][hc], oE[hc], 0, 0, 0);
            oG[hc] = __builtin_amdgcn_mfma_f32_16x16x32_bf16(aG, bvF[kc][hc], oG[hc], 0, 0, 0);
        }
    }
    {
        float* Op = (float*)&wreg[wave][0];
#pragma unroll
        for (int hc = 0; hc < 4; ++hc) {
            *(floatx4*)&Op[(hc * 16 + s) * 16 + quad * 4]        = oE[hc];
            *(floatx4*)&Op[1024 + (hc * 16 + s) * 16 + quad * 4] = oG[hc];
        }
    }
    __syncthreads();

    // ---- phase 4: cross-wave reduce + normalize -> cat bf16 [16 r][136 k] ----
    {
        const int h  = t >> 2;
        const int r4 = (t & 3) * 4;
        floatx4 sE = zero, sG = zero, rE = zero, rG = zero;
#pragma unroll
        for (int w = 0; w < 4; ++w) {
            const float* opw = (const float*)&wreg[w][0];
            sE += *(const floatx4*)&opw[h * 16 + r4];
            sG += *(const floatx4*)&opw[1024 + h * 16 + r4];
            rE += *(const floatx4*)&rowsumP[w][0][r4];
            rG += *(const floatx4*)&rowsumP[w][1][r4];
        }
#pragma unroll
        for (int i = 0; i < 4; ++i) {
            cat_l[(r4 + i) * 136 + h]      = f2bf(sE[i] / rE[i]);
            cat_l[(r4 + i) * 136 + 64 + h] = f2bf(sG[i] / rG[i]);
        }
    }
    __syncthreads();

    // ---- phase 5: out = cat @ Wo^T + bo (wave w -> j in [16w,16w+16)) ----
    {
        floatx4 acc = zero;
#pragma unroll
        for (int kc = 0; kc < 4; ++kc) {
            const short8 aC = *(const short8*)&cat_l[s * 136 + kc * 32 + quad * 8];
            acc = __builtin_amdgcn_mfma_f32_16x16x32_bf16(aC, woF[kc], acc, 0, 0, 0);
        }
        const int j = wave * 16 + s;
#pragma unroll
        for (int reg = 0; reg < 4; ++reg) {
            const int r = quad * 4 + reg;
            if (r < nr) out[(size_t)(m0 + r) * H + j] = acc[reg] + bj;
        }
    }
}

extern "C" void kernel_launch(void* const* d_in, const int* in_sizes, int n_in,
                              void* d_out, int out_size, void* d_ws, size_t ws_size,
                              hipStream_t stream) {
    const float* f_pre_in = (const float*)d_in[0];
    const int*   f_batch  = (const int*)  d_in[1];
    const float* b_pre_in = (const float*)d_in[2];
    const float* bv_in    = (const float*)d_in[3];
    const float* Wf       = (const float*)d_in[4];
    const float* bf       = (const float*)d_in[5];
    const float* Wb       = (const float*)d_in[6];
    const float* bb       = (const float*)d_in[7];
    const float* Wbv      = (const float*)d_in[8];
    const float* bbv      = (const float*)d_in[9];
    const float* Wo       = (const float*)d_in[10];
    const float* bo       = (const float*)d_in[11];
    float* out = (float*)d_out;

    // ws layout (ushort elements, then table)
    unsigned short* f_bf   = (unsigned short*)d_ws;            // 4096*64
    unsigned short* bFT_bf = f_bf + (size_t)M_TOT * H;         // 8*512*64
    unsigned short* bv_bf  = bFT_bf + (size_t)B_TOT * N_TOT * H;
    unsigned short* Wo_bf  = bv_bf + (size_t)B_TOT * H * N_TOT;
    int4* table = (int4*)(Wo_bf + (size_t)H * 2 * H);          // 16B-aligned

    k_pre <<<769, 256, 0, stream>>>(f_pre_in, f_batch, b_pre_in, bv_in,
                                    Wf, bf, Wb, bb, Wbv, bbv, Wo,
                                    f_bf, bFT_bf, bv_bf, Wo_bf, table);
    k_main<<<MAX_TILES, 256, 0, stream>>>(f_bf, bFT_bf, bv_bf, Wo_bf, bo, table, out);
}